// Round 5
// baseline (507.429 us; speedup 1.0000x reference)
//
#include <hip/hip_runtime.h>
#include <hip/hip_bf16.h>
#include <cstdint>
#include <cstddef>

// Problem constants
#define B_    2
#define L_    2048
#define HID_  2048
#define NH_   16
#define NKV_  4
#define HD_   128
#define LAT_  512
#define SCALE_ 0.08838834764831845f   // 1/sqrt(128)
#define SC2_   0.1275174365f          // SCALE * log2(e)

typedef unsigned short u16;
typedef unsigned int   u32;
typedef __attribute__((ext_vector_type(8))) short   short8;
typedef __attribute__((ext_vector_type(4))) float   floatx4;

typedef __attribute__((address_space(1))) const u32 gas_u32;
typedef __attribute__((address_space(3))) u32       las_u32;

__device__ __forceinline__ void gl_lds16(const u16* g, u16* l) {
    // async global->LDS, 16B per lane; LDS dest = wave-uniform base + lane*16
    __builtin_amdgcn_global_load_lds((gas_u32*)g, (las_u32*)l, 16, 0, 0);
}

__device__ __forceinline__ float bf2f(u16 u) {
    union { u32 i; float f; } v; v.i = ((u32)u) << 16; return v.f;
}
__device__ __forceinline__ u16 f2bf(float f) {
    union { float f; u32 u; } v; v.f = f;
    u32 u = v.u;
    u32 r = (u + 0x7fffu + ((u >> 16) & 1u)) >> 16;   // RNE
    return (u16)r;
}

// ---------------- fp32 -> bf16 elementwise ----------------
__global__ void cvt_kernel(const float* __restrict__ in, u16* __restrict__ out, int n) {
    int i = blockIdx.x * 256 + threadIdx.x;
    if (i < n) out[i] = f2bf(in[i]);
}

// ---------------- fp32 [R][C] -> bf16 [C][R] (transpose) ----------------
__global__ void cvt_transpose_kernel(const float* __restrict__ in, u16* __restrict__ out,
                                     int R, int C) {
    __shared__ u16 tile[32][33];
    int c0 = blockIdx.x * 32, r0 = blockIdx.y * 32;
    int tx = threadIdx.x & 31, ty = threadIdx.x >> 5;   // ty in 0..7
    for (int i = ty; i < 32; i += 8)
        tile[tx][i] = f2bf(in[(size_t)(r0 + i) * C + c0 + tx]);
    __syncthreads();
    for (int i = ty; i < 32; i += 8)
        out[(size_t)(c0 + i) * R + r0 + tx] = tile[i][tx];
}

// ---------------- bf16 [b,l,kvh,d] -> bf16 [b,kvh,d,l] (V transpose) ------
__global__ void transpose_v_kernel(const u16* __restrict__ in, u16* __restrict__ out) {
    __shared__ u16 t[32][33];
    int lt = blockIdx.x, dt = blockIdx.y, bh = blockIdx.z;   // bh = b*NKV + kvh
    int b = bh >> 2, kvh = bh & 3;
    int tx = threadIdx.x & 31, ty = threadIdx.x >> 5;
    for (int i = ty; i < 32; i += 8)
        t[i][tx] = in[(((size_t)b * L_ + lt * 32 + i) * NKV_ + kvh) * HD_ + dt * 32 + tx];
    __syncthreads();
    for (int i = ty; i < 32; i += 8)
        out[((size_t)bh * HD_ + dt * 32 + i) * L_ + lt * 32 + tx] = t[tx][i];
}

// ---------------- bf16 GEMM: C[M,N] = A[M,K] * BT[N,K]^T ----------------
// m97 structure: 128x128 tile, BK=32, global_load_lds width-16 staging,
// unpadded LDS (required: lane-linear dest), 2 barriers/iter.
template<int OUT_BF16>
__global__ __launch_bounds__(256)
void gemm_bt(const u16* __restrict__ A, const u16* __restrict__ BT,
             void* __restrict__ C, int M, int N, int K) {
    __shared__ __align__(16) u16 As[128][32];
    __shared__ __align__(16) u16 Bs[128][32];
    const int tid  = threadIdx.x;
    const int m0   = blockIdx.y * 128, n0 = blockIdx.x * 128;
    const int wave = tid >> 6, lane = tid & 63;
    const int wm   = (wave >> 1) * 64, wn = (wave & 1) * 64;
    const int quad = lane >> 4, l16 = lane & 15;

    // staging: wave w fills rows [32w,32w+32); lane L -> row L/4, colseg L%4
    const int srow = wave * 32 + (lane >> 2);
    const int scol = (lane & 3) * 8;
    const u16* aptr0 = A  + (size_t)(m0 + srow) * K + scol;
    const u16* bptr0 = BT + (size_t)(n0 + srow) * K + scol;
    const u16* aptr1 = aptr0 + (size_t)16 * K;
    const u16* bptr1 = bptr0 + (size_t)16 * K;
    u16* lA0 = &As[wave * 32][0];
    u16* lA1 = &As[wave * 32 + 16][0];
    u16* lB0 = &Bs[wave * 32][0];
    u16* lB1 = &Bs[wave * 32 + 16][0];

    floatx4 acc[4][4] = {};

    for (int k0 = 0; k0 < K; k0 += 32) {
        gl_lds16(aptr0 + k0, lA0);
        gl_lds16(aptr1 + k0, lA1);
        gl_lds16(bptr0 + k0, lB0);
        gl_lds16(bptr1 + k0, lB1);
        __syncthreads();   // vmcnt drain + barrier

        short8 af[4], bfr[4];
        #pragma unroll
        for (int i = 0; i < 4; i++) af[i]  = *(const short8*)&As[wm + i * 16 + l16][quad * 8];
        #pragma unroll
        for (int i = 0; i < 4; i++) bfr[i] = *(const short8*)&Bs[wn + i * 16 + l16][quad * 8];
        #pragma unroll
        for (int mi = 0; mi < 4; mi++)
            #pragma unroll
            for (int ni = 0; ni < 4; ni++)
                acc[mi][ni] = __builtin_amdgcn_mfma_f32_16x16x32_bf16(
                    af[mi], bfr[ni], acc[mi][ni], 0, 0, 0);
        __syncthreads();
    }

    #pragma unroll
    for (int mi = 0; mi < 4; mi++) {
        #pragma unroll
        for (int ni = 0; ni < 4; ni++) {
            #pragma unroll
            for (int r = 0; r < 4; r++) {
                int row = m0 + wm + mi * 16 + quad * 4 + r;
                int col = n0 + wn + ni * 16 + l16;
                float v = acc[mi][ni][r];
                if (OUT_BF16) ((u16*)C)[(size_t)row * N + col] = f2bf(v);
                else          ((float*)C)[(size_t)row * N + col] = v;
            }
        }
    }
}

// ---------------- RoPE + head-major permute ----------------
__global__ void rope_perm(const u16* __restrict__ in, u16* __restrict__ out,
                          int nh, int nhbits) {
    int idx = blockIdx.x * 256 + threadIdx.x;   // one thread per (b,h,l,d<64)
    int d = idx & 63;
    int l = (idx >> 6) & (L_ - 1);
    int h = (idx >> 17) & (nh - 1);
    int b = idx >> (17 + nhbits);
    const u16* src = &in[(((size_t)b * L_ + l) * nh + h) * HD_];
    u16* dst = &out[(((size_t)b * nh + h) * L_ + l) * HD_];
    float t1 = bf2f(src[d]), t2 = bf2f(src[d + 64]);
    float inv = expf(-(float)d * 0.14391156831212787f);  // ln(10000)/64
    float fr = (float)l * inv;
    float c = cosf(fr), sn = sinf(fr);
    dst[d]      = f2bf(t1 * c - t2 * sn);
    dst[d + 64] = f2bf(t2 * c + t1 * sn);
}

// ---------------- MFMA flash attention ----------------
// Block = 4 waves = 128 q-rows; 64-key LDS tiles shared by waves.
// bid&7 -> (b,kvh): each XCD's L2 holds one 2 MB K/V set.
// Register-prefetch pipeline: next K/V tile loaded into VGPRs during compute.
// Ps: stride 64 + XOR swizzle (blk ^= ((row>>2)&3) ^ ((row&3)<<1)) -> no 4-way
// quad aliasing on write, reads spread all 32 banks.
// qt pairing: CU gets (15-k, k) -> constant 34 tiles per CU.
__global__ __launch_bounds__(256)
void attn_mfma(const u16* __restrict__ Q, const u16* __restrict__ K,
               const u16* __restrict__ Vt, const int* __restrict__ amask,
               u16* __restrict__ Y) {
    __shared__ __align__(16) u16 Ks[64][136];    // 64 keys x 128 d (+8 pad)
    __shared__ __align__(16) u16 Vs[128][72];    // 128 d x 64 keys (+8 pad)
    __shared__ __align__(16) u16 Ps[4][32][64];  // per-wave, XOR-swizzled
    __shared__ int smask[64];

    const int tid  = threadIdx.x;
    const int wave = tid >> 6, lane = tid & 63;
    const int quad = lane >> 4, l16 = lane & 15;

    const int bid = blockIdx.x;
    const int xcd = bid & 7;
    const int b   = xcd >> 2, kvh = xcd & 3;
    const int g   = bid >> 3;                // 0..63
    const int hq  = g & 3;
    const int gq  = g >> 2;                  // 0..15
    const int qt  = (g < 32) ? (15 - gq) : (gq - 8);   // pair (15-k, k) per CU
    const int h   = kvh * 4 + hq;
    const int q0  = qt * 128 + wave * 32;

    const u16* Qbase = Q  + ((size_t)b * NH_  + h)   * L_ * HD_;
    const u16* Kbase = K  + ((size_t)b * NKV_ + kvh) * L_ * HD_;
    const u16* Vbase = Vt + ((size_t)b * NKV_ + kvh) * (size_t)HD_ * L_;
    const int* mbase = amask + b * L_;

    // Q fragments in registers for the whole kernel
    short8 qa[2][4];
    #pragma unroll
    for (int mi = 0; mi < 2; ++mi)
        #pragma unroll
        for (int ks = 0; ks < 4; ++ks)
            qa[mi][ks] = *(const short8*)&Qbase[(size_t)(q0 + mi * 16 + l16) * HD_ + ks * 32 + quad * 8];

    floatx4 Oacc[2][8] = {};
    float lsum[2][4] = {};

    // staging coords
    const int krow = tid >> 2, kq = (tid & 3) * 32;   // K: quarter-row per thread
    const int vrow = tid >> 1, vh = (tid & 1) * 32;   // V: half-row per thread

    // Ps swizzle helpers
    const int fr_rd = ((l16 >> 2) & 3) ^ ((l16 & 3) << 1);   // f(row=mi*16+l16)

    uint4 ka[4], va[4];
    int mreg = 0;
    auto loadKV = [&](int kbase) {
        const u16* ks = Kbase + (size_t)(kbase + krow) * HD_ + kq;
        ka[0] = *(const uint4*)(ks);
        ka[1] = *(const uint4*)(ks + 8);
        ka[2] = *(const uint4*)(ks + 16);
        ka[3] = *(const uint4*)(ks + 24);
        const u16* vs = Vbase + (size_t)vrow * L_ + kbase + vh;
        va[0] = *(const uint4*)(vs);
        va[1] = *(const uint4*)(vs + 8);
        va[2] = *(const uint4*)(vs + 16);
        va[3] = *(const uint4*)(vs + 24);
        if (tid < 64) mreg = mbase[kbase + tid];
    };

    const int nkt = 2 * qt + 2;
    loadKV(0);

    for (int kt = 0; kt < nkt; ++kt) {
        const int kbase = kt * 64;

        // ---- write prefetched tile to LDS ----
        *(uint4*)&Ks[krow][kq]      = ka[0];
        *(uint4*)&Ks[krow][kq + 8]  = ka[1];
        *(uint4*)&Ks[krow][kq + 16] = ka[2];
        *(uint4*)&Ks[krow][kq + 24] = ka[3];
        *(uint4*)&Vs[vrow][vh]      = va[0];
        *(uint4*)&Vs[vrow][vh + 8]  = va[1];
        *(uint4*)&Vs[vrow][vh + 16] = va[2];
        *(uint4*)&Vs[vrow][vh + 24] = va[3];
        if (tid < 64) smask[tid] = mreg;
        __syncthreads();

        // ---- prefetch next tile into regs (overlaps compute below) ----
        if (kt + 1 < nkt) loadKV(kbase + 64);

        if (kbase <= q0 + 31) {   // causal early-out (barriers stay uniform)
            // ---- S = Q K^T ----
            floatx4 s[2][4] = {};
            #pragma unroll
            for (int ni = 0; ni < 4; ++ni) {
                #pragma unroll
                for (int ks = 0; ks < 4; ++ks) {
                    short8 kf = *(const short8*)&Ks[ni * 16 + l16][ks * 32 + quad * 8];
                    s[0][ni] = __builtin_amdgcn_mfma_f32_16x16x32_bf16(qa[0][ks], kf, s[0][ni], 0, 0, 0);
                    s[1][ni] = __builtin_amdgcn_mfma_f32_16x16x32_bf16(qa[1][ks], kf, s[1][ni], 0, 0, 0);
                }
            }

            int am[4];
            #pragma unroll
            for (int ni = 0; ni < 4; ++ni) am[ni] = smask[ni * 16 + l16];

            // ---- p = exp2(s*SC2 - 8), masked; per-lane l; swizzled pack ----
            #pragma unroll
            for (int mi = 0; mi < 2; ++mi) {
                #pragma unroll
                for (int ni = 0; ni < 4; ++ni) {
                    const int kpos = kbase + ni * 16 + l16;
                    const bool okm = am[ni] > 0;
                    const int blk_log = ni * 2 + (l16 >> 3);
                    const int off = l16 & 7;
                    #pragma unroll
                    for (int r = 0; r < 4; ++r) {
                        const int qrow = q0 + mi * 16 + quad * 4 + r;
                        const bool ok = (kpos <= qrow) & okm;
                        float p = ok ? exp2f(fmaf(s[mi][ni][r], SC2_, -8.0f)) : 0.0f;
                        lsum[mi][r] += p;
                        const int pblk = blk_log ^ quad ^ (r << 1);
                        Ps[wave][mi * 16 + quad * 4 + r][pblk * 8 + off] = f2bf(p);
                    }
                }
            }

            // ---- P: D-layout -> A-layout (per-wave, swizzled read) ----
            short8 pf[2][2];
            #pragma unroll
            for (int mi = 0; mi < 2; ++mi)
                #pragma unroll
                for (int kc = 0; kc < 2; ++kc)
                    pf[mi][kc] = *(const short8*)&Ps[wave][mi * 16 + l16][(((kc * 4 + quad) ^ fr_rd)) * 8];

            // ---- O += P V ----
            #pragma unroll
            for (int kc = 0; kc < 2; ++kc) {
                #pragma unroll
                for (int dn = 0; dn < 8; ++dn) {
                    short8 vf = *(const short8*)&Vs[dn * 16 + l16][kc * 32 + quad * 8];
                    Oacc[0][dn] = __builtin_amdgcn_mfma_f32_16x16x32_bf16(pf[0][kc], vf, Oacc[0][dn], 0, 0, 0);
                    Oacc[1][dn] = __builtin_amdgcn_mfma_f32_16x16x32_bf16(pf[1][kc], vf, Oacc[1][dn], 0, 0, 0);
                }
            }
        }
        __syncthreads();   // Ks/Vs consumed; safe to overwrite next iter
    }

    // ---- epilogue ----
    #pragma unroll
    for (int mi = 0; mi < 2; ++mi) {
        #pragma unroll
        for (int r = 0; r < 4; ++r) {
            float v = lsum[mi][r];
            v += __shfl_xor(v, 1);
            v += __shfl_xor(v, 2);
            v += __shfl_xor(v, 4);
            v += __shfl_xor(v, 8);
            const float linv = 1.0f / v;
            const int qrow = q0 + mi * 16 + quad * 4 + r;
            u16* dst = &Y[(((size_t)b * L_ + qrow) * NH_ + h) * HD_];
            #pragma unroll
            for (int dn = 0; dn < 8; ++dn)
                dst[dn * 16 + l16] = f2bf(Oacc[mi][dn][r] * linv);
        }
    }
}

// ---------------- launch ----------------
extern "C" void kernel_launch(void* const* d_in, const int* in_sizes, int n_in,
                              void* d_out, int out_size, void* d_ws, size_t ws_size,
                              hipStream_t stream) {
    const float* x  = (const float*)d_in[0];
    const float* Wq = (const float*)d_in[1];
    const float* Wc = (const float*)d_in[2];
    const float* Wk = (const float*)d_in[3];
    const float* Wv = (const float*)d_in[4];
    const float* Wo = (const float*)d_in[5];
    const int* amask = (const int*)d_in[6];
    float* out = (float*)d_out;

    char* p = (char*)d_ws;
    auto alloc = [&](size_t elems) {
        u16* r = (u16*)p;
        p += ((elems * 2 + 255) / 256) * 256;
        return r;
    };
    u16* Xb   = alloc((size_t)4096 * 2048);
    u16* WqT  = alloc((size_t)2048 * 2048);
    u16* WcT  = alloc((size_t)512 * 2048);
    u16* WkT  = alloc((size_t)512 * 512);
    u16* WvT  = alloc((size_t)512 * 512);
    u16* WoT  = alloc((size_t)2048 * 2048);
    u16* qbuf = alloc((size_t)4096 * 2048);   // pre-rope q; reused as Y after rope
    u16* Qr   = alloc((size_t)4096 * 2048);
    u16* cbuf = alloc((size_t)4096 * 512);
    u16* kbuf = alloc((size_t)4096 * 512);
    u16* vbuf = alloc((size_t)4096 * 512);
    u16* Kr   = alloc((size_t)4096 * 512);
    u16* Vt   = alloc((size_t)4096 * 512);    // [B, NKV, HD, L]

    // converts
    cvt_kernel<<<8388608 / 256, 256, 0, stream>>>(x, Xb, 8388608);
    cvt_transpose_kernel<<<dim3(2048 / 32, 2048 / 32), 256, 0, stream>>>(Wq, WqT, 2048, 2048);
    cvt_transpose_kernel<<<dim3(512 / 32, 2048 / 32), 256, 0, stream>>>(Wc, WcT, 2048, 512);
    cvt_transpose_kernel<<<dim3(512 / 32, 512 / 32), 256, 0, stream>>>(Wk, WkT, 512, 512);
    cvt_transpose_kernel<<<dim3(512 / 32, 512 / 32), 256, 0, stream>>>(Wv, WvT, 512, 512);
    cvt_transpose_kernel<<<dim3(2048 / 32, 2048 / 32), 256, 0, stream>>>(Wo, WoT, 2048, 2048);

    // projections
    gemm_bt<1><<<dim3(16, 32), 256, 0, stream>>>(Xb, WqT, qbuf, 4096, 2048, 2048);
    gemm_bt<1><<<dim3(4, 32), 256, 0, stream>>>(Xb, WcT, cbuf, 4096, 512, 2048);
    gemm_bt<1><<<dim3(4, 32), 256, 0, stream>>>(cbuf, WkT, kbuf, 4096, 512, 512);
    gemm_bt<1><<<dim3(4, 32), 256, 0, stream>>>(cbuf, WvT, vbuf, 4096, 512, 512);

    // rope + permute to head-major; V -> [b,kvh,d,l]
    rope_perm<<<(2 * 16 * 2048 * 64) / 256, 256, 0, stream>>>(qbuf, Qr, 16, 4);
    rope_perm<<<(2 * 4 * 2048 * 64) / 256, 256, 0, stream>>>(kbuf, Kr, 4, 2);
    transpose_v_kernel<<<dim3(64, 4, 8), 256, 0, stream>>>(vbuf, Vt);

    // attention (writes Y into qbuf, which is dead after rope)
    attn_mfma<<<dim3(512), 256, 0, stream>>>(Qr, Kr, Vt, amask, qbuf);

    // output projection (fp32 out)
    gemm_bt<0><<<dim3(16, 32), 256, 0, stream>>>(qbuf, WoT, out, 4096, 2048, 2048);
}

// Round 6
// 462.338 us; speedup vs baseline: 1.0975x; 1.0975x over previous
//
#include <hip/hip_runtime.h>
#include <hip/hip_bf16.h>
#include <cstdint>
#include <cstddef>

// Problem constants
#define B_    2
#define L_    2048
#define HID_  2048
#define NH_   16
#define NKV_  4
#define HD_   128
#define LAT_  512
#define SCALE_ 0.08838834764831845f   // 1/sqrt(128)
#define SC2_   0.1275174365f          // SCALE * log2(e)

typedef unsigned short u16;
typedef unsigned int   u32;
typedef __attribute__((ext_vector_type(8))) short   short8;
typedef __attribute__((ext_vector_type(4))) float   floatx4;

typedef __attribute__((address_space(1))) const u32 gas_u32;
typedef __attribute__((address_space(3))) u32       las_u32;

__device__ __forceinline__ void gl_lds16(const u16* g, u16* l) {
    // async global->LDS, 16B per lane; LDS dest = wave-uniform base + lane*16
    __builtin_amdgcn_global_load_lds((gas_u32*)g, (las_u32*)l, 16, 0, 0);
}

__device__ __forceinline__ float bf2f(u16 u) {
    union { u32 i; float f; } v; v.i = ((u32)u) << 16; return v.f;
}
__device__ __forceinline__ u16 f2bf(float f) {
    union { float f; u32 u; } v; v.f = f;
    u32 u = v.u;
    u32 r = (u + 0x7fffu + ((u >> 16) & 1u)) >> 16;   // RNE
    return (u16)r;
}

// ---------------- fp32 -> bf16 elementwise ----------------
__global__ void cvt_kernel(const float* __restrict__ in, u16* __restrict__ out, int n) {
    int i = blockIdx.x * 256 + threadIdx.x;
    if (i < n) out[i] = f2bf(in[i]);
}

// ---------------- fp32 [R][C] -> bf16 [C][R] (transpose) ----------------
__global__ void cvt_transpose_kernel(const float* __restrict__ in, u16* __restrict__ out,
                                     int R, int C) {
    __shared__ u16 tile[32][33];
    int c0 = blockIdx.x * 32, r0 = blockIdx.y * 32;
    int tx = threadIdx.x & 31, ty = threadIdx.x >> 5;   // ty in 0..7
    for (int i = ty; i < 32; i += 8)
        tile[tx][i] = f2bf(in[(size_t)(r0 + i) * C + c0 + tx]);
    __syncthreads();
    for (int i = ty; i < 32; i += 8)
        out[(size_t)(c0 + i) * R + r0 + tx] = tile[i][tx];
}

// ---------------- bf16 [b,l,kvh,d] -> bf16 [b,kvh,d,l] (V transpose) ------
__global__ void transpose_v_kernel(const u16* __restrict__ in, u16* __restrict__ out) {
    __shared__ u16 t[32][33];
    int lt = blockIdx.x, dt = blockIdx.y, bh = blockIdx.z;   // bh = b*NKV + kvh
    int b = bh >> 2, kvh = bh & 3;
    int tx = threadIdx.x & 31, ty = threadIdx.x >> 5;
    for (int i = ty; i < 32; i += 8)
        t[i][tx] = in[(((size_t)b * L_ + lt * 32 + i) * NKV_ + kvh) * HD_ + dt * 32 + tx];
    __syncthreads();
    for (int i = ty; i < 32; i += 8)
        out[((size_t)bh * HD_ + dt * 32 + i) * L_ + lt * 32 + tx] = t[tx][i];
}

// ---------------- bf16 GEMM: C[M,N] = A[M,K] * BT[N,K]^T ----------------
// m97 structure: 128x128 tile, BK=32, global_load_lds width-16 staging.
template<int OUT_BF16>
__global__ __launch_bounds__(256)
void gemm_bt(const u16* __restrict__ A, const u16* __restrict__ BT,
             void* __restrict__ C, int M, int N, int K) {
    __shared__ __align__(16) u16 As[128][32];
    __shared__ __align__(16) u16 Bs[128][32];
    const int tid  = threadIdx.x;
    const int m0   = blockIdx.y * 128, n0 = blockIdx.x * 128;
    const int wave = tid >> 6, lane = tid & 63;
    const int wm   = (wave >> 1) * 64, wn = (wave & 1) * 64;
    const int quad = lane >> 4, l16 = lane & 15;

    const int srow = wave * 32 + (lane >> 2);
    const int scol = (lane & 3) * 8;
    const u16* aptr0 = A  + (size_t)(m0 + srow) * K + scol;
    const u16* bptr0 = BT + (size_t)(n0 + srow) * K + scol;
    const u16* aptr1 = aptr0 + (size_t)16 * K;
    const u16* bptr1 = bptr0 + (size_t)16 * K;
    u16* lA0 = &As[wave * 32][0];
    u16* lA1 = &As[wave * 32 + 16][0];
    u16* lB0 = &Bs[wave * 32][0];
    u16* lB1 = &Bs[wave * 32 + 16][0];

    floatx4 acc[4][4] = {};

    for (int k0 = 0; k0 < K; k0 += 32) {
        gl_lds16(aptr0 + k0, lA0);
        gl_lds16(aptr1 + k0, lA1);
        gl_lds16(bptr0 + k0, lB0);
        gl_lds16(bptr1 + k0, lB1);
        __syncthreads();

        short8 af[4], bfr[4];
        #pragma unroll
        for (int i = 0; i < 4; i++) af[i]  = *(const short8*)&As[wm + i * 16 + l16][quad * 8];
        #pragma unroll
        for (int i = 0; i < 4; i++) bfr[i] = *(const short8*)&Bs[wn + i * 16 + l16][quad * 8];
        #pragma unroll
        for (int mi = 0; mi < 4; mi++)
            #pragma unroll
            for (int ni = 0; ni < 4; ni++)
                acc[mi][ni] = __builtin_amdgcn_mfma_f32_16x16x32_bf16(
                    af[mi], bfr[ni], acc[mi][ni], 0, 0, 0);
        __syncthreads();
    }

    #pragma unroll
    for (int mi = 0; mi < 4; mi++) {
        #pragma unroll
        for (int ni = 0; ni < 4; ni++) {
            #pragma unroll
            for (int r = 0; r < 4; r++) {
                int row = m0 + wm + mi * 16 + quad * 4 + r;
                int col = n0 + wn + ni * 16 + l16;
                float v = acc[mi][ni][r];
                if (OUT_BF16) ((u16*)C)[(size_t)row * N + col] = f2bf(v);
                else          ((float*)C)[(size_t)row * N + col] = v;
            }
        }
    }
}

// ---------------- RoPE + head-major permute ----------------
__global__ void rope_perm(const u16* __restrict__ in, u16* __restrict__ out,
                          int nh, int nhbits) {
    int idx = blockIdx.x * 256 + threadIdx.x;   // one thread per (b,h,l,d<64)
    int d = idx & 63;
    int l = (idx >> 6) & (L_ - 1);
    int h = (idx >> 17) & (nh - 1);
    int b = idx >> (17 + nhbits);
    const u16* src = &in[(((size_t)b * L_ + l) * nh + h) * HD_];
    u16* dst = &out[(((size_t)b * nh + h) * L_ + l) * HD_];
    float t1 = bf2f(src[d]), t2 = bf2f(src[d + 64]);
    float inv = expf(-(float)d * 0.14391156831212787f);  // ln(10000)/64
    float fr = (float)l * inv;
    float c = cosf(fr), sn = sinf(fr);
    dst[d]      = f2bf(t1 * c - t2 * sn);
    dst[d + 64] = f2bf(t2 * c + t1 * sn);
}

// ---------------- MFMA flash attention (GQA head-merged waves) -----------
// Block = 4 waves = 4 HEADS of one kv-group, all on the SAME 32 q-rows:
// the staged K/V tile is shared across heads, every wave has an identical
// causal range (no idle waves, uniform barriers).
// bid&7 -> (b,kvh): each XCD's L2 holds one 2 MB K/V set.
// t = 63 - bid>>3: heavy tiles dispatch first (LPT); CU pairs (heavy,light)
// sum to a constant ~33 iterations.
// Max-free softmax: p = exp2(s*SCALE*log2e - 8); shift cancels in O/l.
__global__ __launch_bounds__(256)
void attn_mfma(const u16* __restrict__ Q, const u16* __restrict__ K,
               const u16* __restrict__ Vt, const int* __restrict__ amask,
               u16* __restrict__ Y) {
    __shared__ __align__(16) u16 Ks[64][136];    // 64 keys x 128 d (+8 pad)
    __shared__ __align__(16) u16 Vs[128][72];    // 128 d x 64 keys (+8 pad)
    __shared__ __align__(16) u16 Ps[4][32][64];  // per-wave, XOR-swizzled
    __shared__ int smask[64];

    const int tid  = threadIdx.x;
    const int wave = tid >> 6, lane = tid & 63;
    const int quad = lane >> 4, l16 = lane & 15;

    const int bid = blockIdx.x;
    const int bh  = bid & 7;
    const int b   = bh >> 2, kvh = bh & 3;
    const int t   = 63 - (bid >> 3);         // 32-row q-tile, heavy first
    const int h   = kvh * 4 + wave;          // wave = head
    const int q0  = t * 32;
    const int nkt = (t >> 1) + 1;            // 64-key tiles covering q0+31

    const u16* Qbase = Q  + ((size_t)b * NH_  + h)   * L_ * HD_;
    const u16* Kbase = K  + ((size_t)b * NKV_ + kvh) * L_ * HD_;
    const u16* Vbase = Vt + ((size_t)b * NKV_ + kvh) * (size_t)HD_ * L_;
    const int* mbase = amask + b * L_;

    // Q fragments in registers for the whole kernel
    short8 qa[2][4];
    #pragma unroll
    for (int mi = 0; mi < 2; ++mi)
        #pragma unroll
        for (int ks = 0; ks < 4; ++ks)
            qa[mi][ks] = *(const short8*)&Qbase[(size_t)(q0 + mi * 16 + l16) * HD_ + ks * 32 + quad * 8];

    floatx4 Oacc[2][8] = {};
    float lsum[2][4] = {};

    // staging coords (256 threads cooperate across the block)
    const int krow = tid >> 2, kq = (tid & 3) * 32;   // K: quarter-row per thread
    const int vrow = tid >> 1, vh = (tid & 1) * 32;   // V: half-row per thread

    // Ps swizzle helper for reads
    const int fr_rd = ((l16 >> 2) & 3) ^ ((l16 & 3) << 1);

    for (int kt = 0; kt < nkt; ++kt) {
        const int kbase = kt * 64;

        // ---- stage K tile (64 x 128) : 64B per thread ----
        {
            const u16* src = Kbase + (size_t)(kbase + krow) * HD_ + kq;
            uint4 t0 = *(const uint4*)(src);
            uint4 t1 = *(const uint4*)(src + 8);
            uint4 t2 = *(const uint4*)(src + 16);
            uint4 t3 = *(const uint4*)(src + 24);
            *(uint4*)&Ks[krow][kq]      = t0;
            *(uint4*)&Ks[krow][kq + 8]  = t1;
            *(uint4*)&Ks[krow][kq + 16] = t2;
            *(uint4*)&Ks[krow][kq + 24] = t3;
        }
        // ---- stage V tile (128 x 64) : 64B per thread ----
        {
            const u16* src = Vbase + (size_t)vrow * L_ + kbase + vh;
            uint4 t0 = *(const uint4*)(src);
            uint4 t1 = *(const uint4*)(src + 8);
            uint4 t2 = *(const uint4*)(src + 16);
            uint4 t3 = *(const uint4*)(src + 24);
            *(uint4*)&Vs[vrow][vh]      = t0;
            *(uint4*)&Vs[vrow][vh + 8]  = t1;
            *(uint4*)&Vs[vrow][vh + 16] = t2;
            *(uint4*)&Vs[vrow][vh + 24] = t3;
        }
        if (tid < 64) smask[tid] = mbase[kbase + tid];
        __syncthreads();

        // ---- S = Q K^T : 2 m-tiles x 4 n-tiles x 4 k-steps (K from LDS) ----
        floatx4 s[2][4] = {};
        #pragma unroll
        for (int ni = 0; ni < 4; ++ni) {
            #pragma unroll
            for (int ks = 0; ks < 4; ++ks) {
                short8 kf = *(const short8*)&Ks[ni * 16 + l16][ks * 32 + quad * 8];
                s[0][ni] = __builtin_amdgcn_mfma_f32_16x16x32_bf16(qa[0][ks], kf, s[0][ni], 0, 0, 0);
                s[1][ni] = __builtin_amdgcn_mfma_f32_16x16x32_bf16(qa[1][ks], kf, s[1][ni], 0, 0, 0);
            }
        }

        int am[4];
        #pragma unroll
        for (int ni = 0; ni < 4; ++ni) am[ni] = smask[ni * 16 + l16];

        // ---- p = exp2(s*SC2 - 8), masked; per-lane l; swizzled pack ----
        #pragma unroll
        for (int mi = 0; mi < 2; ++mi) {
            #pragma unroll
            for (int ni = 0; ni < 4; ++ni) {
                const int kpos = kbase + ni * 16 + l16;
                const bool okm = am[ni] > 0;
                const int blk_log = ni * 2 + (l16 >> 3);
                const int off = l16 & 7;
                #pragma unroll
                for (int r = 0; r < 4; ++r) {
                    const int qrow = q0 + mi * 16 + quad * 4 + r;
                    const bool ok = (kpos <= qrow) & okm;
                    float p = ok ? exp2f(fmaf(s[mi][ni][r], SC2_, -8.0f)) : 0.0f;
                    lsum[mi][r] += p;
                    const int pblk = blk_log ^ quad ^ (r << 1);
                    Ps[wave][mi * 16 + quad * 4 + r][pblk * 8 + off] = f2bf(p);
                }
            }
        }

        // ---- P: D-layout -> A-layout (per-wave, swizzled read) ----
        short8 pf[2][2];
        #pragma unroll
        for (int mi = 0; mi < 2; ++mi)
            #pragma unroll
            for (int kc = 0; kc < 2; ++kc)
                pf[mi][kc] = *(const short8*)&Ps[wave][mi * 16 + l16][(((kc * 4 + quad) ^ fr_rd)) * 8];

        // ---- O += P V (V from LDS) ----
        #pragma unroll
        for (int kc = 0; kc < 2; ++kc) {
            #pragma unroll
            for (int dn = 0; dn < 8; ++dn) {
                short8 vf = *(const short8*)&Vs[dn * 16 + l16][kc * 32 + quad * 8];
                Oacc[0][dn] = __builtin_amdgcn_mfma_f32_16x16x32_bf16(pf[0][kc], vf, Oacc[0][dn], 0, 0, 0);
                Oacc[1][dn] = __builtin_amdgcn_mfma_f32_16x16x32_bf16(pf[1][kc], vf, Oacc[1][dn], 0, 0, 0);
            }
        }
        __syncthreads();   // Ks/Vs consumed; safe to overwrite next iter
    }

    // ---- epilogue: reduce l across the 16-lane row group, write Y ----
    #pragma unroll
    for (int mi = 0; mi < 2; ++mi) {
        #pragma unroll
        for (int r = 0; r < 4; ++r) {
            float v = lsum[mi][r];
            v += __shfl_xor(v, 1);
            v += __shfl_xor(v, 2);
            v += __shfl_xor(v, 4);
            v += __shfl_xor(v, 8);
            const float linv = 1.0f / v;
            const int qrow = q0 + mi * 16 + quad * 4 + r;
            u16* dst = &Y[(((size_t)b * L_ + qrow) * NH_ + h) * HD_];
            #pragma unroll
            for (int dn = 0; dn < 8; ++dn)
                dst[dn * 16 + l16] = f2bf(Oacc[mi][dn][r] * linv);
        }
    }
}

// ---------------- launch ----------------
extern "C" void kernel_launch(void* const* d_in, const int* in_sizes, int n_in,
                              void* d_out, int out_size, void* d_ws, size_t ws_size,
                              hipStream_t stream) {
    const float* x  = (const float*)d_in[0];
    const float* Wq = (const float*)d_in[1];
    const float* Wc = (const float*)d_in[2];
    const float* Wk = (const float*)d_in[3];
    const float* Wv = (const float*)d_in[4];
    const float* Wo = (const float*)d_in[5];
    const int* amask = (const int*)d_in[6];
    float* out = (float*)d_out;

    char* p = (char*)d_ws;
    auto alloc = [&](size_t elems) {
        u16* r = (u16*)p;
        p += ((elems * 2 + 255) / 256) * 256;
        return r;
    };
    u16* Xb   = alloc((size_t)4096 * 2048);
    u16* WqT  = alloc((size_t)2048 * 2048);
    u16* WcT  = alloc((size_t)512 * 2048);
    u16* WkT  = alloc((size_t)512 * 512);
    u16* WvT  = alloc((size_t)512 * 512);
    u16* WoT  = alloc((size_t)2048 * 2048);
    u16* qbuf = alloc((size_t)4096 * 2048);   // pre-rope q; reused as Y after rope
    u16* Qr   = alloc((size_t)4096 * 2048);
    u16* cbuf = alloc((size_t)4096 * 512);
    u16* kbuf = alloc((size_t)4096 * 512);
    u16* vbuf = alloc((size_t)4096 * 512);
    u16* Kr   = alloc((size_t)4096 * 512);
    u16* Vt   = alloc((size_t)4096 * 512);    // [B, NKV, HD, L]

    // converts
    cvt_kernel<<<8388608 / 256, 256, 0, stream>>>(x, Xb, 8388608);
    cvt_transpose_kernel<<<dim3(2048 / 32, 2048 / 32), 256, 0, stream>>>(Wq, WqT, 2048, 2048);
    cvt_transpose_kernel<<<dim3(512 / 32, 2048 / 32), 256, 0, stream>>>(Wc, WcT, 2048, 512);
    cvt_transpose_kernel<<<dim3(512 / 32, 512 / 32), 256, 0, stream>>>(Wk, WkT, 512, 512);
    cvt_transpose_kernel<<<dim3(512 / 32, 512 / 32), 256, 0, stream>>>(Wv, WvT, 512, 512);
    cvt_transpose_kernel<<<dim3(2048 / 32, 2048 / 32), 256, 0, stream>>>(Wo, WoT, 2048, 2048);

    // projections
    gemm_bt<1><<<dim3(16, 32), 256, 0, stream>>>(Xb, WqT, qbuf, 4096, 2048, 2048);
    gemm_bt<1><<<dim3(4, 32), 256, 0, stream>>>(Xb, WcT, cbuf, 4096, 512, 2048);
    gemm_bt<1><<<dim3(4, 32), 256, 0, stream>>>(cbuf, WkT, kbuf, 4096, 512, 512);
    gemm_bt<1><<<dim3(4, 32), 256, 0, stream>>>(cbuf, WvT, vbuf, 4096, 512, 512);

    // rope + permute to head-major; V -> [b,kvh,d,l]
    rope_perm<<<(2 * 16 * 2048 * 64) / 256, 256, 0, stream>>>(qbuf, Qr, 16, 4);
    rope_perm<<<(2 * 4 * 2048 * 64) / 256, 256, 0, stream>>>(kbuf, Kr, 4, 2);
    transpose_v_kernel<<<dim3(64, 4, 8), 256, 0, stream>>>(vbuf, Vt);

    // attention (writes Y into qbuf, which is dead after rope)
    attn_mfma<<<dim3(512), 256, 0, stream>>>(Qr, Kr, Vt, amask, qbuf);

    // output projection (fp32 out)
    gemm_bt<0><<<dim3(16, 32), 256, 0, stream>>>(qbuf, WoT, out, 4096, 2048, 2048);
}